// Round 18
// baseline (139.368 us; speedup 1.0000x reference)
//
#include <hip/hip_runtime.h>
#include <hip/hip_fp16.h>
#include <float.h>
#include <math.h>

// Problem constants (B=8, N=2048, C=64, k=32, out=[64,128])
#define NB    8
#define NP    2048
#define NC    64
#define NK    32
#define NCAND 96      // candidate buffer per query (cnt ~53, P(>96) negligible)
#define RSEL  48      // rank-threshold on the pre-reduced pool
#define NO2   128

typedef __attribute__((ext_vector_type(8))) short short8v;   // 8 bf16 (4 VGPRs)
typedef __attribute__((ext_vector_type(4))) float f32x4;

__device__ __forceinline__ unsigned short f2bf(float f) {    // RNE f32->bf16
    unsigned u = __float_as_uint(f);
    return (unsigned short)((u + 0x7fffu + ((u >> 16) & 1u)) >> 16);
}

// sortable-u16 key from raw fp16 bits (ascending distance -> ascending key)
__device__ __forceinline__ unsigned h2key(unsigned u) {
    return (u & 0x8000u) ? (u ^ 0xFFFFu) : (u | 0x8000u);
}

// packed per-half u16 min/max of two u32 words
__device__ __forceinline__ unsigned pmin16(unsigned a, unsigned b) {
    unsigned lo = min(a & 0xFFFFu, b & 0xFFFFu);
    unsigned hi = min(a >> 16, b >> 16);
    return lo | (hi << 16);
}
__device__ __forceinline__ unsigned pmax16(unsigned a, unsigned b) {
    unsigned lo = max(a & 0xFFFFu, b & 0xFFFFu);
    unsigned hi = max(a >> 16, b >> 16);
    return lo | (hi << 16);
}

// ---------------------------------------------------------------------------
// Kernel P: prep — Ysb = bf16((x.W1a^T)*s1), Ks = (x.(W1b-W1a)^T)*s1 + b1,
// W2 packed to bf16, PLUS fused xcvt: xbf (bf16 copy), sqf/sq64 (norms).
// One wave per 4 points; lane = output channel.
// ---------------------------------------------------------------------------
__global__ __launch_bounds__(256) void prep_kernel(
    const float* __restrict__ x, const float* __restrict__ W1,
    const float* __restrict__ g1, const float* __restrict__ b1,
    const float* __restrict__ W2,
    unsigned short* __restrict__ Ysb, float* __restrict__ Ks,
    unsigned short* __restrict__ W2bf,
    unsigned short* __restrict__ xbf, float* __restrict__ sqf,
    double* __restrict__ sq64)
{
    const int t = threadIdx.x;
    const int w = t >> 6, l = t & 63;
    const float invbn = 1.0f / sqrtf(1.0f + 1e-5f);

    if (blockIdx.x == 0 && t < 128) {
        const float4* src = reinterpret_cast<const float4*>(W2 + (size_t)t * 64);
        ushort4* dst = reinterpret_cast<ushort4*>(W2bf + (size_t)t * 64);
#pragma unroll
        for (int i = 0; i < 16; ++i) {
            float4 v = src[i];
            ushort4 pk = { f2bf(v.x), f2bf(v.y), f2bf(v.z), f2bf(v.w) };
            dst[i] = pk;
        }
    }

    float was[64], wds[64];
    const float s1v = g1[l] * invbn;
    const float b1v = b1[l];
#pragma unroll
    for (int c4 = 0; c4 < 16; ++c4) {
        float4 lo = reinterpret_cast<const float4*>(W1 + (size_t)l * 128)[c4];
        float4 hi = reinterpret_cast<const float4*>(W1 + (size_t)l * 128 + 64)[c4];
        was[c4*4+0] = lo.x * s1v; was[c4*4+1] = lo.y * s1v;
        was[c4*4+2] = lo.z * s1v; was[c4*4+3] = lo.w * s1v;
        wds[c4*4+0] = (hi.x - lo.x) * s1v; wds[c4*4+1] = (hi.y - lo.y) * s1v;
        wds[c4*4+2] = (hi.z - lo.z) * s1v; wds[c4*4+3] = (hi.w - lo.w) * s1v;
    }

    const int pbase = (blockIdx.x * 4 + w) * 4;
#pragma unroll 1
    for (int i = 0; i < 4; ++i) {
        const int p = pbase + i;
        const float* xr = x + (size_t)p * NC;
        float y0 = 0.f, y1 = 0.f, k0 = 0.f, k1 = 0.f;
        double s64 = 0.0;
#pragma unroll
        for (int c4 = 0; c4 < 16; ++c4) {
            float4 v = reinterpret_cast<const float4*>(xr)[c4];
            y0 = fmaf(v.x, was[c4*4+0], y0); y1 = fmaf(v.y, was[c4*4+1], y1);
            y0 = fmaf(v.z, was[c4*4+2], y0); y1 = fmaf(v.w, was[c4*4+3], y1);
            k0 = fmaf(v.x, wds[c4*4+0], k0); k1 = fmaf(v.y, wds[c4*4+1], k1);
            k0 = fmaf(v.z, wds[c4*4+2], k0); k1 = fmaf(v.w, wds[c4*4+3], k1);
            s64 += (double)v.x * v.x + (double)v.y * v.y
                 + (double)v.z * v.z + (double)v.w * v.w;
        }
        Ysb[(size_t)p * NC + l] = f2bf(y0 + y1);
        Ks[(size_t)p * NC + l] = (k0 + k1) + b1v;
        xbf[(size_t)p * NC + l] = f2bf(xr[l]);          // fused xcvt (L1-hot)
        if (l == 0) { sq64[p] = s64; sqf[p] = (float)s64; }
    }
}

// ---------------------------------------------------------------------------
// Kernel D: distance matrix via bf16 MFMA. Block = 32 queries x 512 points
// (4 waves x 128 pts). Keys (h2key of fp16 d) accumulate in a wave-private
// LDS tile [32 q][128 pts] (pad 136), then stream out FULL-WIDTH: 16-lane
// subgroups own 4 consecutive query rows, 16 B/lane.
// ---------------------------------------------------------------------------
__global__ __launch_bounds__(256) void dist_kernel(const unsigned short* __restrict__ xbf,
                                                   const float* __restrict__ sqf,
                                                   unsigned short* __restrict__ D,
                                                   int qstart) {
    __shared__ unsigned short xq[32][72];
    __shared__ float sqq_l[32];
    __shared__ unsigned short kq[4][32][136];   // per-wave transpose tile
    const int t = threadIdx.x;
    const int w = t >> 6, l = t & 63;
    const int li = l & 15, g = l >> 4;
    const int qt32 = blockIdx.x >> 2, mq = blockIdx.x & 3;
    const int qbase = qstart + qt32 * 32;
    const int b = qbase >> 11;
    const size_t xrowb = (size_t)b * NP;

    {   // stage 32 query rows (bf16) + norms
        int row = t >> 3, seg = t & 7;
        uint4 vv = *reinterpret_cast<const uint4*>(xbf + (size_t)(qbase + row) * NC + seg * 8);
        *reinterpret_cast<uint4*>(&xq[row][seg * 8]) = vv;
        if (t < 32) sqq_l[t] = sqf[(size_t)qbase + t];
    }
    __syncthreads();

    short8v bq[2][2];
#pragma unroll
    for (int qt = 0; qt < 2; ++qt)
#pragma unroll
        for (int kk = 0; kk < 2; ++kk)
            bq[qt][kk] = *reinterpret_cast<const short8v*>(&xq[qt * 16 + li][kk * 32 + g * 8]);
    const float sqq0 = sqq_l[li], sqq1 = sqq_l[16 + li];

    const int mwbase = mq * 512 + w * 128;
#pragma unroll 2
    for (int mt = 0; mt < 8; ++mt) {
        const int m16 = mwbase + mt * 16;
        const unsigned short* arow = xbf + (xrowb + m16 + li) * NC + g * 8;
        short8v a0 = *reinterpret_cast<const short8v*>(arow);
        short8v a1 = *reinterpret_cast<const short8v*>(arow + 32);
        float4 sqm = *reinterpret_cast<const float4*>(sqf + xrowb + m16 + g * 4);
#pragma unroll
        for (int qt = 0; qt < 2; ++qt) {
            f32x4 acc = {0.f, 0.f, 0.f, 0.f};
            acc = __builtin_amdgcn_mfma_f32_16x16x32_bf16(a0, bq[qt][0], acc, 0, 0, 0);
            acc = __builtin_amdgcn_mfma_f32_16x16x32_bf16(a1, bq[qt][1], acc, 0, 0, 0);
            const float sqq = qt ? sqq1 : sqq0;
            ushort4 hv;
            hv.x = (unsigned short)h2key(__half_as_ushort(__float2half(sqm.x + sqq - 2.f * acc[0])));
            hv.y = (unsigned short)h2key(__half_as_ushort(__float2half(sqm.y + sqq - 2.f * acc[1])));
            hv.z = (unsigned short)h2key(__half_as_ushort(__float2half(sqm.z + sqq - 2.f * acc[2])));
            hv.w = (unsigned short)h2key(__half_as_ushort(__float2half(sqm.w + sqq - 2.f * acc[3])));
            *reinterpret_cast<ushort4*>(&kq[w][qt * 16 + li][mt * 16 + g * 4]) = hv;
        }
    }

    // stream out full-width: subgroup (l>>4) owns row qq+(l>>4), 16 B/lane
    {
        const int qg4 = l >> 4, lx = l & 15;
#pragma unroll
        for (int qq = 0; qq < 32; qq += 4) {
            uint4 v4 = *reinterpret_cast<const uint4*>(&kq[w][qq + qg4][lx * 8]);
            *reinterpret_cast<uint4*>(
                &D[(size_t)(qbase - qstart + qq + qg4) * NP + mwbase + lx * 8]) = v4;
        }
    }
}

// ---------------------------------------------------------------------------
// Kernel S: fused select + refine (R12 structure; R18: refine dot split into
// 4 independent f64 accumulators + sq64 hoisted above the gather loop —
// serial f64 chain 64 -> 16 FMAs).
// ---------------------------------------------------------------------------
__global__ __launch_bounds__(256) void select_refine_kernel(
    const unsigned short* __restrict__ D,
    const float* __restrict__ x,
    const double* __restrict__ sq64,
    unsigned short* __restrict__ idxout,
    int qstart)
{
    __shared__ unsigned short cnd[4][NCAND];
    __shared__ float qrow[4][64];
    __shared__ double2 kd2[4][NCAND];

    const int t = threadIdx.x, w = t >> 6, l = t & 63;
    const int qrel = blockIdx.x * 4 + w;
    const int q = qstart + qrel;
    const size_t bbase = (size_t)(q >> 11) << 11;
    const unsigned short* Drow = D + (size_t)qrel * NP;

    // stage my wave's q-row (fp32) early
    if (l < 16)
        reinterpret_cast<float4*>(qrow[w])[l] =
            reinterpret_cast<const float4*>(x + (size_t)q * NC)[l];

    // load my 32 keys, packed 2-per-u32 (16 VGPRs, statically indexed)
    unsigned kp[16];
#pragma unroll
    for (int c = 0; c < 4; ++c) {
        uint4 r4 = *reinterpret_cast<const uint4*>(Drow + c * 512 + l * 8);
        kp[c * 4 + 0] = r4.x; kp[c * 4 + 1] = r4.y;
        kp[c * 4 + 2] = r4.z; kp[c * 4 + 3] = r4.w;
    }

    // quarter minima: qm[c] = min of kp[4c..4c+3] (8 u16 keys)
    unsigned qm0, qm1, qm2, qm3;
    {
        unsigned m0 = pmin16(pmin16(kp[0], kp[1]),  pmin16(kp[2], kp[3]));
        unsigned m1 = pmin16(pmin16(kp[4], kp[5]),  pmin16(kp[6], kp[7]));
        unsigned m2 = pmin16(pmin16(kp[8], kp[9]),  pmin16(kp[10], kp[11]));
        unsigned m3 = pmin16(pmin16(kp[12], kp[13]), pmin16(kp[14], kp[15]));
        qm0 = min(m0 & 0xFFFFu, m0 >> 16);
        qm1 = min(m1 & 0xFFFFu, m1 >> 16);
        qm2 = min(m2 & 0xFFFFu, m2 >> 16);
        qm3 = min(m3 & 0xFFFFu, m3 >> 16);
    }

    // bisection bounds from pool min/max (12 shfl ops)
    unsigned lo, hi;
    {
        unsigned mn = min(min(qm0, qm1), min(qm2, qm3));
        unsigned mx = max(max(qm0, qm1), max(qm2, qm3));
#pragma unroll
        for (int off = 1; off < 64; off <<= 1) {
            mn = min(mn, (unsigned)__shfl_xor((int)mn, off));
            mx = max(mx, (unsigned)__shfl_xor((int)mx, off));
        }
        lo = mn; hi = mx;
    }

    // wave-uniform bisection: smallest Kstar with pool-count(<=Kstar) >= RSEL
    while (lo < hi) {
        const unsigned mid = lo + ((hi - lo) >> 1);
        unsigned cc = (unsigned)__popcll(__ballot(qm0 <= mid))
                    + (unsigned)__popcll(__ballot(qm1 <= mid))
                    + (unsigned)__popcll(__ballot(qm2 <= mid))
                    + (unsigned)__popcll(__ballot(qm3 <= mid));
        if (cc >= RSEL) hi = mid; else lo = mid + 1;
    }
    const unsigned Kstar = hi;

    // compaction: per-lane count + exclusive prefix scan, lane-major order
    unsigned mycnt = 0;
#pragma unroll
    for (int i = 0; i < 16; ++i) {
        mycnt += ((kp[i] & 0xFFFFu) <= Kstar) ? 1u : 0u;
        mycnt += ((kp[i] >> 16)     <= Kstar) ? 1u : 0u;
    }
    unsigned inc = mycnt;
#pragma unroll
    for (int off = 1; off < 64; off <<= 1) {
        unsigned tmp = __shfl_up(inc, off);
        if (l >= off) inc += tmp;
    }
    const unsigned total = (unsigned)__shfl((int)inc, 63);
    unsigned pos = inc - mycnt;
#pragma unroll
    for (int i = 0; i < 32; ++i) {
        const unsigned kk = (i & 1) ? (kp[i >> 1] >> 16) : (kp[i >> 1] & 0xFFFFu);
        if (kk <= Kstar && pos < NCAND) {
            const int c = i >> 3, j = (i >> 1) & 3, hlf = i & 1;
            cnd[w][pos] = (unsigned short)(c * 512 + l * 8 + j * 2 + hlf);
            ++pos;
        }
    }
    const int cnt_c = (int)(total < NCAND ? total : NCAND);

    // fp64 exact keys: 4 independent accumulator chains, sq64 issued early
    for (int base = 0; base < cnt_c; base += 64) {
        const int slot = base + l;
        const bool valid = slot < cnt_c;
        const int m = valid ? (int)cnd[w][slot] : 0;
        const float* rowm = x + (bbase + m) * NC;
        const double sqm = sq64[bbase + m];          // overlaps with gathers
        double d0 = 0, d1 = 0, d2 = 0, d3 = 0;
#pragma unroll
        for (int c4 = 0; c4 < 16; c4 += 4) {
            float4 a0 = reinterpret_cast<const float4*>(qrow[w])[c4 + 0];
            float4 b0 = reinterpret_cast<const float4*>(rowm)[c4 + 0];
            float4 a1 = reinterpret_cast<const float4*>(qrow[w])[c4 + 1];
            float4 b1 = reinterpret_cast<const float4*>(rowm)[c4 + 1];
            float4 a2 = reinterpret_cast<const float4*>(qrow[w])[c4 + 2];
            float4 b2 = reinterpret_cast<const float4*>(rowm)[c4 + 2];
            float4 a3 = reinterpret_cast<const float4*>(qrow[w])[c4 + 3];
            float4 b3 = reinterpret_cast<const float4*>(rowm)[c4 + 3];
            d0 += (double)a0.x * b0.x + (double)a0.y * b0.y
                + (double)a0.z * b0.z + (double)a0.w * b0.w;
            d1 += (double)a1.x * b1.x + (double)a1.y * b1.y
                + (double)a1.z * b1.z + (double)a1.w * b1.w;
            d2 += (double)a2.x * b2.x + (double)a2.y * b2.y
                + (double)a2.z * b2.z + (double)a2.w * b2.w;
            d3 += (double)a3.x * b3.x + (double)a3.y * b3.y
                + (double)a3.z * b3.z + (double)a3.w * b3.w;
        }
        if (valid)
            kd2[w][slot] = make_double2(
                sqm - 2.0 * ((d0 + d1) + (d2 + d3)), (double)m);
    }

    // all-pairs rank, write top-32
    for (int base = 0; base < cnt_c; base += 64) {
        const int slot = base + l;
        const bool valid = slot < cnt_c;
        const int m = valid ? (int)cnd[w][slot] : 0;
        double key = 1e300, mid = 0.0;
        if (valid) { double2 kk = kd2[w][slot]; key = kk.x; mid = kk.y; }
        int rank = 0;
#pragma unroll 4
        for (int j = 0; j < cnt_c; ++j) {
            double2 o = kd2[w][j];
            rank += (o.x < key || (o.x == key && o.y < mid)) ? 1 : 0;
        }
        if (valid && rank < NK)
            idxout[(size_t)q * NK + rank] = (unsigned short)m;
    }
}

// ---------------------------------------------------------------------------
// Kernel B: conv2 v2 — A-fragments gathered DIRECTLY from Ysb in fragment
// layout. Ks-add + LReLU + bf16-pack in-register. LDS = W2 only.
// ---------------------------------------------------------------------------
__global__ __launch_bounds__(256) void conv2_kernel(
    const unsigned short* __restrict__ Ysb, const float* __restrict__ Ks,
    const unsigned short* __restrict__ W2bf,
    const float* __restrict__ g2, const float* __restrict__ b2,
    const unsigned short* __restrict__ idx16, float* __restrict__ out)
{
    __shared__ short w2l[128 * 72];

    const int t = threadIdx.x;
    const int w = t >> 6, l = t & 63;
    const int g = l >> 4, li = l & 15;
    const int p = blockIdx.x * 4 + w;
    const size_t bbase = (size_t)(p >> 11) << 11;
    const float invbn = 1.0f / sqrtf(1.0f + 1e-5f);

    {   // stage W2bf -> LDS (2 threads per row)
        const int r = t >> 1, half = t & 1;
        const uint4* src = reinterpret_cast<const uint4*>(W2bf + (size_t)r * 64 + half * 32);
        uint4* dst = reinterpret_cast<uint4*>(&w2l[r * 72 + half * 32]);
#pragma unroll
        for (int i = 0; i < 4; ++i) dst[i] = src[i];
    }

    float g2r[8], b2r[8];
#pragma unroll
    for (int nt = 0; nt < 8; ++nt) {
        g2r[nt] = g2[nt * 16 + li] * invbn;
        b2r[nt] = b2[nt * 16 + li];
    }

    // neighbor rows this lane owns (A rows mt2*16+li)
    const int j0 = idx16[(size_t)p * NK + li];
    const int j1 = idx16[(size_t)p * NK + 16 + li];

    // Ks for channels kt*32+g*8 .. +8 (contiguous)
    float ksf[2][8];
#pragma unroll
    for (int kt = 0; kt < 2; ++kt) {
        float4 ka = reinterpret_cast<const float4*>(Ks + (size_t)p * NC)[kt * 8 + g * 2];
        float4 kb = reinterpret_cast<const float4*>(Ks + (size_t)p * NC)[kt * 8 + g * 2 + 1];
        ksf[kt][0] = ka.x; ksf[kt][1] = ka.y; ksf[kt][2] = ka.z; ksf[kt][3] = ka.w;
        ksf[kt][4] = kb.x; ksf[kt][5] = kb.y; ksf[kt][6] = kb.z; ksf[kt][7] = kb.w;
    }

    // build A fragments directly from gathered Ysb rows
    short8v a[2][2];
#pragma unroll
    for (int mt2 = 0; mt2 < 2; ++mt2) {
        const int j = mt2 ? j1 : j0;
        const unsigned short* yrow = Ysb + (bbase + j) * NC;
#pragma unroll
        for (int kt = 0; kt < 2; ++kt) {
            ushort4 v0 = *reinterpret_cast<const ushort4*>(yrow + kt * 32 + g * 8);
            ushort4 v1 = *reinterpret_cast<const ushort4*>(yrow + kt * 32 + g * 8 + 4);
            short8v frag;
            float h;
            h = __uint_as_float((unsigned)v0.x << 16) + ksf[kt][0]; h = h > 0.f ? h : 0.01f * h; frag[0] = (short)f2bf(h);
            h = __uint_as_float((unsigned)v0.y << 16) + ksf[kt][1]; h = h > 0.f ? h : 0.01f * h; frag[1] = (short)f2bf(h);
            h = __uint_as_float((unsigned)v0.z << 16) + ksf[kt][2]; h = h > 0.f ? h : 0.01f * h; frag[2] = (short)f2bf(h);
            h = __uint_as_float((unsigned)v0.w << 16) + ksf[kt][3]; h = h > 0.f ? h : 0.01f * h; frag[3] = (short)f2bf(h);
            h = __uint_as_float((unsigned)v1.x << 16) + ksf[kt][4]; h = h > 0.f ? h : 0.01f * h; frag[4] = (short)f2bf(h);
            h = __uint_as_float((unsigned)v1.y << 16) + ksf[kt][5]; h = h > 0.f ? h : 0.01f * h; frag[5] = (short)f2bf(h);
            h = __uint_as_float((unsigned)v1.z << 16) + ksf[kt][6]; h = h > 0.f ? h : 0.01f * h; frag[6] = (short)f2bf(h);
            h = __uint_as_float((unsigned)v1.w << 16) + ksf[kt][7]; h = h > 0.f ? h : 0.01f * h; frag[7] = (short)f2bf(h);
            a[mt2][kt] = frag;
        }
    }
    __syncthreads();   // w2l ready

#pragma unroll 1
    for (int nt = 0; nt < 8; ++nt) {
        short8v b0 = *reinterpret_cast<const short8v*>(&w2l[(nt * 16 + li) * 72 + g * 8]);
        short8v b1 = *reinterpret_cast<const short8v*>(&w2l[(nt * 16 + li) * 72 + 32 + g * 8]);
        f32x4 acc0 = {0.f, 0.f, 0.f, 0.f};
        f32x4 acc1 = {0.f, 0.f, 0.f, 0.f};
        acc0 = __builtin_amdgcn_mfma_f32_16x16x32_bf16(a[0][0], b0, acc0, 0, 0, 0);
        acc0 = __builtin_amdgcn_mfma_f32_16x16x32_bf16(a[0][1], b1, acc0, 0, 0, 0);
        acc1 = __builtin_amdgcn_mfma_f32_16x16x32_bf16(a[1][0], b0, acc1, 0, 0, 0);
        acc1 = __builtin_amdgcn_mfma_f32_16x16x32_bf16(a[1][1], b1, acc1, 0, 0, 0);

        const float s2v = g2r[nt], c2v = b2r[nt];
        float mx = -FLT_MAX;
#pragma unroll
        for (int r = 0; r < 4; ++r) {
            float hA = acc0[r] * s2v + c2v; hA = hA > 0.f ? hA : 0.01f * hA;
            float hB = acc1[r] * s2v + c2v; hB = hB > 0.f ? hB : 0.01f * hB;
            mx = fmaxf(mx, fmaxf(hA, hB));
        }
        mx = fmaxf(mx, __shfl_xor(mx, 16));
        mx = fmaxf(mx, __shfl_xor(mx, 32));
        if (l < 16) out[(size_t)p * NO2 + nt * 16 + l] = mx;
    }
}

// ---------------------------------------------------------------------------
extern "C" void kernel_launch(void* const* d_in, const int* in_sizes, int n_in,
                              void* d_out, int out_size, void* d_ws, size_t ws_size,
                              hipStream_t stream) {
    const float* x  = (const float*)d_in[0];
    const float* W1 = (const float*)d_in[1];
    const float* g1 = (const float*)d_in[2];
    const float* b1 = (const float*)d_in[3];
    const float* W2 = (const float*)d_in[4];
    const float* g2 = (const float*)d_in[5];
    const float* b2 = (const float*)d_in[6];
    float* out = (float*)d_out;

    // workspace layout (fixed 9,650,176 B + D-chunk)
    char* ws = (char*)d_ws;
    unsigned short* xbf  = (unsigned short*)(ws);              // 2,097,152
    float*          sqf  = (float*)(ws + 2097152);             //    65,536
    double*         sq64 = (double*)(ws + 2162688);            //   131,072
    unsigned short* idxw = (unsigned short*)(ws + 2293760);    // 1,048,576
    unsigned short* Ysbw = (unsigned short*)(ws + 3342336);    // 2,097,152
    float*          Ksw  = (float*)(ws + 5439488);             // 4,194,304
    unsigned short* w2bfw= (unsigned short*)(ws + 9633792);    //    16,384
    unsigned short* Dw   = (unsigned short*)(ws + 9650176);    // qch*4KB

    size_t avail = ws_size > 9650176 ? ws_size - 9650176 : 0;
    int qch = NB * NP;                                         // 16384 queries
    while (qch > 64 && (size_t)qch * NP * 2 > avail) qch >>= 1;

    prep_kernel<<<1024, 256, 0, stream>>>(x, W1, g1, b1, W2, Ysbw, Ksw, w2bfw,
                                          xbf, sqf, sq64);
    for (int qs = 0; qs < NB * NP; qs += qch) {
        dist_kernel         <<<qch / 8, 256, 0, stream>>>(xbf, sqf, Dw, qs);
        select_refine_kernel<<<qch / 4, 256, 0, stream>>>(Dw, x, sq64, idxw, qs);
    }
    conv2_kernel <<<NB * NP / 4, 256, 0, stream>>>(Ysbw, Ksw, w2bfw, g2, b2, idxw, out);
}

// Round 19
// 136.273 us; speedup vs baseline: 1.0227x; 1.0227x over previous
//
#include <hip/hip_runtime.h>
#include <hip/hip_fp16.h>
#include <float.h>
#include <math.h>

// Problem constants (B=8, N=2048, C=64, k=32, out=[64,128])
#define NB    8
#define NP    2048
#define NC    64
#define NK    32
#define NCAND 96      // candidate buffer per query (cnt ~53, P(>96) negligible)
#define RSEL  48      // rank-threshold on the pre-reduced pool
#define NO2   128

typedef __attribute__((ext_vector_type(8))) short short8v;   // 8 bf16 (4 VGPRs)
typedef __attribute__((ext_vector_type(4))) float f32x4;

__device__ __forceinline__ unsigned short f2bf(float f) {    // RNE f32->bf16
    unsigned u = __float_as_uint(f);
    return (unsigned short)((u + 0x7fffu + ((u >> 16) & 1u)) >> 16);
}

// sortable-u16 key from raw fp16 bits (ascending distance -> ascending key)
__device__ __forceinline__ unsigned h2key(unsigned u) {
    return (u & 0x8000u) ? (u ^ 0xFFFFu) : (u | 0x8000u);
}

// packed per-half u16 min/max of two u32 words
__device__ __forceinline__ unsigned pmin16(unsigned a, unsigned b) {
    unsigned lo = min(a & 0xFFFFu, b & 0xFFFFu);
    unsigned hi = min(a >> 16, b >> 16);
    return lo | (hi << 16);
}
__device__ __forceinline__ unsigned pmax16(unsigned a, unsigned b) {
    unsigned lo = max(a & 0xFFFFu, b & 0xFFFFu);
    unsigned hi = max(a >> 16, b >> 16);
    return lo | (hi << 16);
}

// ---------------------------------------------------------------------------
// Kernel P: prep — Ysb = bf16((x.W1a^T)*s1), Ks = (x.(W1b-W1a)^T)*s1 + b1,
// W2 packed to bf16, PLUS fused xcvt: xbf (bf16 copy), sqf/sq64 (norms).
// One wave per 4 points; lane = output channel.
// ---------------------------------------------------------------------------
__global__ __launch_bounds__(256) void prep_kernel(
    const float* __restrict__ x, const float* __restrict__ W1,
    const float* __restrict__ g1, const float* __restrict__ b1,
    const float* __restrict__ W2,
    unsigned short* __restrict__ Ysb, float* __restrict__ Ks,
    unsigned short* __restrict__ W2bf,
    unsigned short* __restrict__ xbf, float* __restrict__ sqf,
    double* __restrict__ sq64)
{
    const int t = threadIdx.x;
    const int w = t >> 6, l = t & 63;
    const float invbn = 1.0f / sqrtf(1.0f + 1e-5f);

    if (blockIdx.x == 0 && t < 128) {
        const float4* src = reinterpret_cast<const float4*>(W2 + (size_t)t * 64);
        ushort4* dst = reinterpret_cast<ushort4*>(W2bf + (size_t)t * 64);
#pragma unroll
        for (int i = 0; i < 16; ++i) {
            float4 v = src[i];
            ushort4 pk = { f2bf(v.x), f2bf(v.y), f2bf(v.z), f2bf(v.w) };
            dst[i] = pk;
        }
    }

    float was[64], wds[64];
    const float s1v = g1[l] * invbn;
    const float b1v = b1[l];
#pragma unroll
    for (int c4 = 0; c4 < 16; ++c4) {
        float4 lo = reinterpret_cast<const float4*>(W1 + (size_t)l * 128)[c4];
        float4 hi = reinterpret_cast<const float4*>(W1 + (size_t)l * 128 + 64)[c4];
        was[c4*4+0] = lo.x * s1v; was[c4*4+1] = lo.y * s1v;
        was[c4*4+2] = lo.z * s1v; was[c4*4+3] = lo.w * s1v;
        wds[c4*4+0] = (hi.x - lo.x) * s1v; wds[c4*4+1] = (hi.y - lo.y) * s1v;
        wds[c4*4+2] = (hi.z - lo.z) * s1v; wds[c4*4+3] = (hi.w - lo.w) * s1v;
    }

    const int pbase = (blockIdx.x * 4 + w) * 4;
#pragma unroll 1
    for (int i = 0; i < 4; ++i) {
        const int p = pbase + i;
        const float* xr = x + (size_t)p * NC;
        float y0 = 0.f, y1 = 0.f, k0 = 0.f, k1 = 0.f;
        double s64 = 0.0;
#pragma unroll
        for (int c4 = 0; c4 < 16; ++c4) {
            float4 v = reinterpret_cast<const float4*>(xr)[c4];
            y0 = fmaf(v.x, was[c4*4+0], y0); y1 = fmaf(v.y, was[c4*4+1], y1);
            y0 = fmaf(v.z, was[c4*4+2], y0); y1 = fmaf(v.w, was[c4*4+3], y1);
            k0 = fmaf(v.x, wds[c4*4+0], k0); k1 = fmaf(v.y, wds[c4*4+1], k1);
            k0 = fmaf(v.z, wds[c4*4+2], k0); k1 = fmaf(v.w, wds[c4*4+3], k1);
            s64 += (double)v.x * v.x + (double)v.y * v.y
                 + (double)v.z * v.z + (double)v.w * v.w;
        }
        Ysb[(size_t)p * NC + l] = f2bf(y0 + y1);
        Ks[(size_t)p * NC + l] = (k0 + k1) + b1v;
        xbf[(size_t)p * NC + l] = f2bf(xr[l]);          // fused xcvt (L1-hot)
        if (l == 0) { sq64[p] = s64; sqf[p] = (float)s64; }
    }
}

// ---------------------------------------------------------------------------
// Kernel D: distance matrix via bf16 MFMA. Block = 32 queries x 512 points
// (4 waves x 128 pts). Keys (h2key of fp16 d) accumulate in a wave-private
// LDS tile [32 q][128 pts] (pad 136), then stream out FULL-WIDTH: 16-lane
// subgroups own 4 consecutive query rows, 16 B/lane.
// ---------------------------------------------------------------------------
__global__ __launch_bounds__(256) void dist_kernel(const unsigned short* __restrict__ xbf,
                                                   const float* __restrict__ sqf,
                                                   unsigned short* __restrict__ D,
                                                   int qstart) {
    __shared__ unsigned short xq[32][72];
    __shared__ float sqq_l[32];
    __shared__ unsigned short kq[4][32][136];   // per-wave transpose tile
    const int t = threadIdx.x;
    const int w = t >> 6, l = t & 63;
    const int li = l & 15, g = l >> 4;
    const int qt32 = blockIdx.x >> 2, mq = blockIdx.x & 3;
    const int qbase = qstart + qt32 * 32;
    const int b = qbase >> 11;
    const size_t xrowb = (size_t)b * NP;

    {   // stage 32 query rows (bf16) + norms
        int row = t >> 3, seg = t & 7;
        uint4 vv = *reinterpret_cast<const uint4*>(xbf + (size_t)(qbase + row) * NC + seg * 8);
        *reinterpret_cast<uint4*>(&xq[row][seg * 8]) = vv;
        if (t < 32) sqq_l[t] = sqf[(size_t)qbase + t];
    }
    __syncthreads();

    short8v bq[2][2];
#pragma unroll
    for (int qt = 0; qt < 2; ++qt)
#pragma unroll
        for (int kk = 0; kk < 2; ++kk)
            bq[qt][kk] = *reinterpret_cast<const short8v*>(&xq[qt * 16 + li][kk * 32 + g * 8]);
    const float sqq0 = sqq_l[li], sqq1 = sqq_l[16 + li];

    const int mwbase = mq * 512 + w * 128;
#pragma unroll 2
    for (int mt = 0; mt < 8; ++mt) {
        const int m16 = mwbase + mt * 16;
        const unsigned short* arow = xbf + (xrowb + m16 + li) * NC + g * 8;
        short8v a0 = *reinterpret_cast<const short8v*>(arow);
        short8v a1 = *reinterpret_cast<const short8v*>(arow + 32);
        float4 sqm = *reinterpret_cast<const float4*>(sqf + xrowb + m16 + g * 4);
#pragma unroll
        for (int qt = 0; qt < 2; ++qt) {
            f32x4 acc = {0.f, 0.f, 0.f, 0.f};
            acc = __builtin_amdgcn_mfma_f32_16x16x32_bf16(a0, bq[qt][0], acc, 0, 0, 0);
            acc = __builtin_amdgcn_mfma_f32_16x16x32_bf16(a1, bq[qt][1], acc, 0, 0, 0);
            const float sqq = qt ? sqq1 : sqq0;
            ushort4 hv;
            hv.x = (unsigned short)h2key(__half_as_ushort(__float2half(sqm.x + sqq - 2.f * acc[0])));
            hv.y = (unsigned short)h2key(__half_as_ushort(__float2half(sqm.y + sqq - 2.f * acc[1])));
            hv.z = (unsigned short)h2key(__half_as_ushort(__float2half(sqm.z + sqq - 2.f * acc[2])));
            hv.w = (unsigned short)h2key(__half_as_ushort(__float2half(sqm.w + sqq - 2.f * acc[3])));
            *reinterpret_cast<ushort4*>(&kq[w][qt * 16 + li][mt * 16 + g * 4]) = hv;
        }
    }

    // stream out full-width: subgroup (l>>4) owns row qq+(l>>4), 16 B/lane
    {
        const int qg4 = l >> 4, lx = l & 15;
#pragma unroll
        for (int qq = 0; qq < 32; qq += 4) {
            uint4 v4 = *reinterpret_cast<const uint4*>(&kq[w][qq + qg4][lx * 8]);
            *reinterpret_cast<uint4*>(
                &D[(size_t)(qbase - qstart + qq + qg4) * NP + mwbase + lx * 8]) = v4;
        }
    }
}

// ---------------------------------------------------------------------------
// Kernel S: fused select + refine (R12 version — verified local optimum;
// R18's f64-chain split was tested and regressed, reverted).
// ---------------------------------------------------------------------------
__global__ __launch_bounds__(256) void select_refine_kernel(
    const unsigned short* __restrict__ D,
    const float* __restrict__ x,
    const double* __restrict__ sq64,
    unsigned short* __restrict__ idxout,
    int qstart)
{
    __shared__ unsigned short cnd[4][NCAND];
    __shared__ float qrow[4][64];
    __shared__ double2 kd2[4][NCAND];

    const int t = threadIdx.x, w = t >> 6, l = t & 63;
    const int qrel = blockIdx.x * 4 + w;
    const int q = qstart + qrel;
    const size_t bbase = (size_t)(q >> 11) << 11;
    const unsigned short* Drow = D + (size_t)qrel * NP;

    // stage my wave's q-row (fp32) early
    if (l < 16)
        reinterpret_cast<float4*>(qrow[w])[l] =
            reinterpret_cast<const float4*>(x + (size_t)q * NC)[l];

    // load my 32 keys, packed 2-per-u32 (16 VGPRs, statically indexed)
    unsigned kp[16];
#pragma unroll
    for (int c = 0; c < 4; ++c) {
        uint4 r4 = *reinterpret_cast<const uint4*>(Drow + c * 512 + l * 8);
        kp[c * 4 + 0] = r4.x; kp[c * 4 + 1] = r4.y;
        kp[c * 4 + 2] = r4.z; kp[c * 4 + 3] = r4.w;
    }

    // quarter minima: qm[c] = min of kp[4c..4c+3] (8 u16 keys)
    unsigned qm0, qm1, qm2, qm3;
    {
        unsigned m0 = pmin16(pmin16(kp[0], kp[1]),  pmin16(kp[2], kp[3]));
        unsigned m1 = pmin16(pmin16(kp[4], kp[5]),  pmin16(kp[6], kp[7]));
        unsigned m2 = pmin16(pmin16(kp[8], kp[9]),  pmin16(kp[10], kp[11]));
        unsigned m3 = pmin16(pmin16(kp[12], kp[13]), pmin16(kp[14], kp[15]));
        qm0 = min(m0 & 0xFFFFu, m0 >> 16);
        qm1 = min(m1 & 0xFFFFu, m1 >> 16);
        qm2 = min(m2 & 0xFFFFu, m2 >> 16);
        qm3 = min(m3 & 0xFFFFu, m3 >> 16);
    }

    // bisection bounds from pool min/max (12 shfl ops)
    unsigned lo, hi;
    {
        unsigned mn = min(min(qm0, qm1), min(qm2, qm3));
        unsigned mx = max(max(qm0, qm1), max(qm2, qm3));
#pragma unroll
        for (int off = 1; off < 64; off <<= 1) {
            mn = min(mn, (unsigned)__shfl_xor((int)mn, off));
            mx = max(mx, (unsigned)__shfl_xor((int)mx, off));
        }
        lo = mn; hi = mx;
    }

    // wave-uniform bisection: smallest Kstar with pool-count(<=Kstar) >= RSEL
    while (lo < hi) {
        const unsigned mid = lo + ((hi - lo) >> 1);
        unsigned cc = (unsigned)__popcll(__ballot(qm0 <= mid))
                    + (unsigned)__popcll(__ballot(qm1 <= mid))
                    + (unsigned)__popcll(__ballot(qm2 <= mid))
                    + (unsigned)__popcll(__ballot(qm3 <= mid));
        if (cc >= RSEL) hi = mid; else lo = mid + 1;
    }
    const unsigned Kstar = hi;

    // compaction: per-lane count + exclusive prefix scan, lane-major order
    unsigned mycnt = 0;
#pragma unroll
    for (int i = 0; i < 16; ++i) {
        mycnt += ((kp[i] & 0xFFFFu) <= Kstar) ? 1u : 0u;
        mycnt += ((kp[i] >> 16)     <= Kstar) ? 1u : 0u;
    }
    unsigned inc = mycnt;
#pragma unroll
    for (int off = 1; off < 64; off <<= 1) {
        unsigned tmp = __shfl_up(inc, off);
        if (l >= off) inc += tmp;
    }
    const unsigned total = (unsigned)__shfl((int)inc, 63);
    unsigned pos = inc - mycnt;
#pragma unroll
    for (int i = 0; i < 32; ++i) {
        const unsigned kk = (i & 1) ? (kp[i >> 1] >> 16) : (kp[i >> 1] & 0xFFFFu);
        if (kk <= Kstar && pos < NCAND) {
            const int c = i >> 3, j = (i >> 1) & 3, hlf = i & 1;
            cnd[w][pos] = (unsigned short)(c * 512 + l * 8 + j * 2 + hlf);
            ++pos;
        }
    }
    const int cnt_c = (int)(total < NCAND ? total : NCAND);

    // fp64 exact keys for candidates (1 pass typically; 2 if cnt > 64)
    for (int base = 0; base < cnt_c; base += 64) {
        const int slot = base + l;
        const bool valid = slot < cnt_c;
        const int m = valid ? (int)cnd[w][slot] : 0;
        const float* rowm = x + (bbase + m) * NC;
        double dot = 0;
#pragma unroll
        for (int c4 = 0; c4 < 16; ++c4) {
            float4 a  = reinterpret_cast<const float4*>(qrow[w])[c4];  // LDS broadcast
            float4 bb = reinterpret_cast<const float4*>(rowm)[c4];
            dot += (double)a.x * bb.x + (double)a.y * bb.y
                 + (double)a.z * bb.z + (double)a.w * bb.w;
        }
        if (valid)
            kd2[w][slot] = make_double2(sq64[bbase + m] - 2.0 * dot, (double)m);
    }

    // all-pairs rank, write top-32
    for (int base = 0; base < cnt_c; base += 64) {
        const int slot = base + l;
        const bool valid = slot < cnt_c;
        const int m = valid ? (int)cnd[w][slot] : 0;
        double key = 1e300, mid = 0.0;
        if (valid) { double2 kk = kd2[w][slot]; key = kk.x; mid = kk.y; }
        int rank = 0;
#pragma unroll 4
        for (int j = 0; j < cnt_c; ++j) {
            double2 o = kd2[w][j];
            rank += (o.x < key || (o.x == key && o.y < mid)) ? 1 : 0;
        }
        if (valid && rank < NK)
            idxout[(size_t)q * NK + rank] = (unsigned short)m;
    }
}

// ---------------------------------------------------------------------------
// Kernel B: conv2 v2 — A-fragments gathered DIRECTLY from Ysb in fragment
// layout. Ks-add + LReLU + bf16-pack in-register. LDS = W2 only.
// ---------------------------------------------------------------------------
__global__ __launch_bounds__(256) void conv2_kernel(
    const unsigned short* __restrict__ Ysb, const float* __restrict__ Ks,
    const unsigned short* __restrict__ W2bf,
    const float* __restrict__ g2, const float* __restrict__ b2,
    const unsigned short* __restrict__ idx16, float* __restrict__ out)
{
    __shared__ short w2l[128 * 72];

    const int t = threadIdx.x;
    const int w = t >> 6, l = t & 63;
    const int g = l >> 4, li = l & 15;
    const int p = blockIdx.x * 4 + w;
    const size_t bbase = (size_t)(p >> 11) << 11;
    const float invbn = 1.0f / sqrtf(1.0f + 1e-5f);

    {   // stage W2bf -> LDS (2 threads per row)
        const int r = t >> 1, half = t & 1;
        const uint4* src = reinterpret_cast<const uint4*>(W2bf + (size_t)r * 64 + half * 32);
        uint4* dst = reinterpret_cast<uint4*>(&w2l[r * 72 + half * 32]);
#pragma unroll
        for (int i = 0; i < 4; ++i) dst[i] = src[i];
    }

    float g2r[8], b2r[8];
#pragma unroll
    for (int nt = 0; nt < 8; ++nt) {
        g2r[nt] = g2[nt * 16 + li] * invbn;
        b2r[nt] = b2[nt * 16 + li];
    }

    // neighbor rows this lane owns (A rows mt2*16+li)
    const int j0 = idx16[(size_t)p * NK + li];
    const int j1 = idx16[(size_t)p * NK + 16 + li];

    // Ks for channels kt*32+g*8 .. +8 (contiguous)
    float ksf[2][8];
#pragma unroll
    for (int kt = 0; kt < 2; ++kt) {
        float4 ka = reinterpret_cast<const float4*>(Ks + (size_t)p * NC)[kt * 8 + g * 2];
        float4 kb = reinterpret_cast<const float4*>(Ks + (size_t)p * NC)[kt * 8 + g * 2 + 1];
        ksf[kt][0] = ka.x; ksf[kt][1] = ka.y; ksf[kt][2] = ka.z; ksf[kt][3] = ka.w;
        ksf[kt][4] = kb.x; ksf[kt][5] = kb.y; ksf[kt][6] = kb.z; ksf[kt][7] = kb.w;
    }

    // build A fragments directly from gathered Ysb rows
    short8v a[2][2];
#pragma unroll
    for (int mt2 = 0; mt2 < 2; ++mt2) {
        const int j = mt2 ? j1 : j0;
        const unsigned short* yrow = Ysb + (bbase + j) * NC;
#pragma unroll
        for (int kt = 0; kt < 2; ++kt) {
            ushort4 v0 = *reinterpret_cast<const ushort4*>(yrow + kt * 32 + g * 8);
            ushort4 v1 = *reinterpret_cast<const ushort4*>(yrow + kt * 32 + g * 8 + 4);
            short8v frag;
            float h;
            h = __uint_as_float((unsigned)v0.x << 16) + ksf[kt][0]; h = h > 0.f ? h : 0.01f * h; frag[0] = (short)f2bf(h);
            h = __uint_as_float((unsigned)v0.y << 16) + ksf[kt][1]; h = h > 0.f ? h : 0.01f * h; frag[1] = (short)f2bf(h);
            h = __uint_as_float((unsigned)v0.z << 16) + ksf[kt][2]; h = h > 0.f ? h : 0.01f * h; frag[2] = (short)f2bf(h);
            h = __uint_as_float((unsigned)v0.w << 16) + ksf[kt][3]; h = h > 0.f ? h : 0.01f * h; frag[3] = (short)f2bf(h);
            h = __uint_as_float((unsigned)v1.x << 16) + ksf[kt][4]; h = h > 0.f ? h : 0.01f * h; frag[4] = (short)f2bf(h);
            h = __uint_as_float((unsigned)v1.y << 16) + ksf[kt][5]; h = h > 0.f ? h : 0.01f * h; frag[5] = (short)f2bf(h);
            h = __uint_as_float((unsigned)v1.z << 16) + ksf[kt][6]; h = h > 0.f ? h : 0.01f * h; frag[6] = (short)f2bf(h);
            h = __uint_as_float((unsigned)v1.w << 16) + ksf[kt][7]; h = h > 0.f ? h : 0.01f * h; frag[7] = (short)f2bf(h);
            a[mt2][kt] = frag;
        }
    }
    __syncthreads();   // w2l ready

#pragma unroll 1
    for (int nt = 0; nt < 8; ++nt) {
        short8v b0 = *reinterpret_cast<const short8v*>(&w2l[(nt * 16 + li) * 72 + g * 8]);
        short8v b1 = *reinterpret_cast<const short8v*>(&w2l[(nt * 16 + li) * 72 + 32 + g * 8]);
        f32x4 acc0 = {0.f, 0.f, 0.f, 0.f};
        f32x4 acc1 = {0.f, 0.f, 0.f, 0.f};
        acc0 = __builtin_amdgcn_mfma_f32_16x16x32_bf16(a[0][0], b0, acc0, 0, 0, 0);
        acc0 = __builtin_amdgcn_mfma_f32_16x16x32_bf16(a[0][1], b1, acc0, 0, 0, 0);
        acc1 = __builtin_amdgcn_mfma_f32_16x16x32_bf16(a[1][0], b0, acc1, 0, 0, 0);
        acc1 = __builtin_amdgcn_mfma_f32_16x16x32_bf16(a[1][1], b1, acc1, 0, 0, 0);

        const float s2v = g2r[nt], c2v = b2r[nt];
        float mx = -FLT_MAX;
#pragma unroll
        for (int r = 0; r < 4; ++r) {
            float hA = acc0[r] * s2v + c2v; hA = hA > 0.f ? hA : 0.01f * hA;
            float hB = acc1[r] * s2v + c2v; hB = hB > 0.f ? hB : 0.01f * hB;
            mx = fmaxf(mx, fmaxf(hA, hB));
        }
        mx = fmaxf(mx, __shfl_xor(mx, 16));
        mx = fmaxf(mx, __shfl_xor(mx, 32));
        if (l < 16) out[(size_t)p * NO2 + nt * 16 + l] = mx;
    }
}

// ---------------------------------------------------------------------------
extern "C" void kernel_launch(void* const* d_in, const int* in_sizes, int n_in,
                              void* d_out, int out_size, void* d_ws, size_t ws_size,
                              hipStream_t stream) {
    const float* x  = (const float*)d_in[0];
    const float* W1 = (const float*)d_in[1];
    const float* g1 = (const float*)d_in[2];
    const float* b1 = (const float*)d_in[3];
    const float* W2 = (const float*)d_in[4];
    const float* g2 = (const float*)d_in[5];
    const float* b2 = (const float*)d_in[6];
    float* out = (float*)d_out;

    // workspace layout (fixed 9,650,176 B + D-chunk)
    char* ws = (char*)d_ws;
    unsigned short* xbf  = (unsigned short*)(ws);              // 2,097,152
    float*          sqf  = (float*)(ws + 2097152);             //    65,536
    double*         sq64 = (double*)(ws + 2162688);            //   131,072
    unsigned short* idxw = (unsigned short*)(ws + 2293760);    // 1,048,576
    unsigned short* Ysbw = (unsigned short*)(ws + 3342336);    // 2,097,152
    float*          Ksw  = (float*)(ws + 5439488);             // 4,194,304
    unsigned short* w2bfw= (unsigned short*)(ws + 9633792);    //    16,384
    unsigned short* Dw   = (unsigned short*)(ws + 9650176);    // qch*4KB

    size_t avail = ws_size > 9650176 ? ws_size - 9650176 : 0;
    int qch = NB * NP;                                         // 16384 queries
    while (qch > 64 && (size_t)qch * NP * 2 > avail) qch >>= 1;

    prep_kernel<<<1024, 256, 0, stream>>>(x, W1, g1, b1, W2, Ysbw, Ksw, w2bfw,
                                          xbf, sqf, sq64);
    for (int qs = 0; qs < NB * NP; qs += qch) {
        dist_kernel         <<<qch / 8, 256, 0, stream>>>(xbf, sqf, Dw, qs);
        select_refine_kernel<<<qch / 4, 256, 0, stream>>>(Dw, x, sq64, idxw, qs);
    }
    conv2_kernel <<<NB * NP / 4, 256, 0, stream>>>(Ysbw, Ksw, w2bfw, g2, b2, idxw, out);
}